// Round 7
// baseline (358.532 us; speedup 1.0000x reference)
//
#include <hip/hip_runtime.h>

// Problem constants
#define B 8
#define T 768
#define D 1024
#define H 16
#define DH 64
#define M (B*T)      // 6144
#define N3 (3*D)     // 3072
#define KDIM D       // 1024
#define QKV_ELEMS (B*H*T*DH)  // 6291456 floats per tensor
#define XE ((size_t)M * KDIM)    // 6291456
#define WE ((size_t)N3 * KDIM)   // 3145728

typedef __attribute__((ext_vector_type(8))) short bf16x8;
typedef __attribute__((ext_vector_type(4))) short bf16x4;
typedef __attribute__((ext_vector_type(4))) float f32x4;

__device__ __forceinline__ unsigned short f2bf(float x) {
    union { float f; unsigned u; } a; a.f = x;
    unsigned r = a.u + 0x7FFFu + ((a.u >> 16) & 1u);
    return (unsigned short)(r >> 16);
}
__device__ __forceinline__ float bf2f(unsigned short h) {
    union { unsigned u; float f; } a; a.u = ((unsigned)h) << 16;
    return a.f;
}

// async global->LDS, 16B per lane; LDS dest is wave-uniform base (HW adds lane*16)
__device__ __forceinline__ void gload_lds16(const void* g, void* l) {
    __builtin_amdgcn_global_load_lds(
        (const __attribute__((address_space(1))) void*)g,
        (__attribute__((address_space(3))) void*)l, 16, 0, 0);
}

// ---------------- Kernel 1: RoPE tables ----------------
__global__ void rope_tables_kernel(float* __restrict__ cosT, float* __restrict__ sinT) {
    int idx = blockIdx.x * blockDim.x + threadIdx.x;  // t*32 + i
    if (idx >= T * 32) return;
    int t = idx >> 5;
    int i = idx & 31;
    float inv_freq = powf(10000.0f, -(float)(2 * i) / 64.0f);
    float ang = (float)t * inv_freq;
    cosT[idx] = cosf(ang);
    sinT[idx] = sinf(ang);
}

// ---------------- Kernel 1b: fp32 -> bf16 hi/lo split (offline, once) ----------------
__global__ __launch_bounds__(256) void split_convert_kernel(
    const float* __restrict__ src, unsigned short* __restrict__ hi,
    unsigned short* __restrict__ lo, int n8)
{
    int i = blockIdx.x * blockDim.x + threadIdx.x;
    if (i >= n8) return;
    const float* p = src + (size_t)i * 8;
    float v[8];
    *(float4*)&v[0] = ((const float4*)p)[0];
    *(float4*)&v[4] = ((const float4*)p)[1];
    union { unsigned short u[8]; uint4 q; } hu, lu;
#pragma unroll
    for (int e = 0; e < 8; ++e) {
        unsigned short h = f2bf(v[e]);
        hu.u[e] = h;
        lu.u[e] = f2bf(v[e] - bf2f(h));
    }
    ((uint4*)hi)[i] = hu.q;
    ((uint4*)lo)[i] = lu.q;
}

#define BMq 128
#define BNq 128
#define BKq 32

// ---------------- Kernel 2 (fast): QKV GEMM, pre-split + gload_lds + 2-phase dbuf ----------------
// LDS tiles [row][32k] bf16 linear dest; global source pre-swizzled with the r5-verified
// conflict-free involution q ^= (row>>1)&3; matching swizzle on ds_read_b128.
// 2-phase: STAGE(t+1) issued BEFORE compute(t); single barrier per k-step after compute
// so the global-load latency hides under ds_read+MFMA (T3 minimum recipe).
__global__ __launch_bounds__(256) void qkv_mfma2_kernel(
    const unsigned short* __restrict__ Xhi, const unsigned short* __restrict__ Xlo,
    const unsigned short* __restrict__ Whi, const unsigned short* __restrict__ Wlo,
    const float* __restrict__ bias, const float* __restrict__ cosT,
    const float* __restrict__ sinT, float* __restrict__ qr,
    float* __restrict__ kr, float* __restrict__ vr)
{
    __shared__ unsigned short Ah[2][BMq * BKq], Al[2][BMq * BKq];
    __shared__ unsigned short Bh[2][BNq * BKq], Bl[2][BNq * BKq];   // 64 KB total

    const int tid  = threadIdx.x;
    const int lane = tid & 63;
    const int w    = tid >> 6;      // wave 0..3
    const int wr   = w >> 1;        // wave row 0..1
    const int wc   = w & 1;         // wave col 0..1
    const int lr   = lane & 15;
    const int kc   = lane >> 4;     // k-quarter 0..3

    const int m0 = blockIdx.x * BMq;
    const int n0 = blockIdx.y * BNq;

    f32x4 acc[4][4];
#pragma unroll
    for (int m = 0; m < 4; ++m)
#pragma unroll
        for (int n = 0; n < 4; ++n) acc[m][n] = (f32x4){0.f, 0.f, 0.f, 0.f};

    auto stage = [&](int bufi, int k0s) {
#pragma unroll
        for (int i = 0; i < 2; ++i) {
            int c   = w * 128 + i * 64 + lane;              // 16B-chunk index 0..511
            int row = c >> 2;
            int qq  = (c & 3) ^ ((row >> 1) & 3);           // pre-swizzled source quarter
            size_t goffA = (size_t)(m0 + row) * KDIM + k0s + qq * 8;
            size_t goffB = (size_t)(n0 + row) * KDIM + k0s + qq * 8;
            int lbase = (w * 128 + i * 64) * 8;             // wave-uniform LDS base (ushort idx)
            gload_lds16(Xhi + goffA, &Ah[bufi][lbase]);
            gload_lds16(Xlo + goffA, &Al[bufi][lbase]);
            gload_lds16(Whi + goffB, &Bh[bufi][lbase]);
            gload_lds16(Wlo + goffB, &Bl[bufi][lbase]);
        }
    };

    stage(0, 0);
    __syncthreads();            // vmcnt(0) drain + barrier: buf0 ready
    int cur = 0;

    for (int t = 0; t < KDIM / BKq; ++t) {
        if (t < KDIM / BKq - 1) stage(cur ^ 1, (t + 1) * BKq);   // prefetch next tile

        // ---- fragment loads (swizzled) from buf[cur] ----
        bf16x8 ah[4], al[4], bh[4], bl[4];
#pragma unroll
        for (int m = 0; m < 4; ++m) {
            int r = wr * 64 + m * 16 + lr;
            int idx = r * 32 + (kc ^ ((r >> 1) & 3)) * 8;
            ah[m] = *(const bf16x8*)&Ah[cur][idx];
            al[m] = *(const bf16x8*)&Al[cur][idx];
        }
#pragma unroll
        for (int n = 0; n < 4; ++n) {
            int ccol = wc * 64 + n * 16 + lr;
            int idx = ccol * 32 + (kc ^ ((ccol >> 1) & 3)) * 8;
            bh[n] = *(const bf16x8*)&Bh[cur][idx];
            bl[n] = *(const bf16x8*)&Bl[cur][idx];
        }

        // ---- MFMA: hi*hi + hi*lo + lo*hi ----
#pragma unroll
        for (int m = 0; m < 4; ++m)
#pragma unroll
            for (int n = 0; n < 4; ++n) {
                acc[m][n] = __builtin_amdgcn_mfma_f32_16x16x32_bf16(ah[m], bh[n], acc[m][n], 0, 0, 0);
                acc[m][n] = __builtin_amdgcn_mfma_f32_16x16x32_bf16(ah[m], bl[n], acc[m][n], 0, 0, 0);
                acc[m][n] = __builtin_amdgcn_mfma_f32_16x16x32_bf16(al[m], bh[n], acc[m][n], 0, 0, 0);
            }

        __syncthreads();        // drain t+1 loads (mostly landed under compute) + sync
        cur ^= 1;
    }

    // ---- epilogue: bias + RoPE + scatter to (B,H,T,DH) [verified r3] ----
    const int section = n0 >> 10;                       // 0=q,1=k,2=v
    float* dst = (section == 0) ? qr : (section == 1) ? kr : vr;
    const int hcol = ((n0 & 1023) >> 6) + wc;           // head index

    float biasv[2][2];
#pragma unroll
    for (int np = 0; np < 2; ++np) {
        biasv[np][0] = bias[n0 + wc * 64 + np * 16 + lr];
        biasv[np][1] = bias[n0 + wc * 64 + np * 16 + lr + 32];
    }

#pragma unroll
    for (int m = 0; m < 4; ++m) {
#pragma unroll
        for (int j = 0; j < 4; ++j) {
            int grow = m0 + wr * 64 + m * 16 + (lane >> 4) * 4 + j;
            int bidx = grow / T;
            int t = grow - bidx * T;
            float* rowp = dst + (((size_t)bidx * H + hcol) * T + t) * DH;
#pragma unroll
            for (int np = 0; np < 2; ++np) {
                int d = np * 16 + lr;                   // 0..31
                float vlo = acc[m][np][j]     + biasv[np][0];
                float vhi = acc[m][np + 2][j] + biasv[np][1];
                if (section < 2) {
                    float c = cosT[t * 32 + d];
                    float s = sinT[t * 32 + d];
                    float nl = vlo * c - vhi * s;
                    float nh = vhi * c + vlo * s;
                    vlo = nl; vhi = nh;
                }
                rowp[d]      = vlo;
                rowp[d + 32] = vhi;
            }
        }
    }
}

// ---------------- Kernel 2 (fallback, r5-verified): in-loop split ----------------
__global__ __launch_bounds__(256) void qkv_mfma_kernel(
    const float* __restrict__ X, const float* __restrict__ W,
    const float* __restrict__ bias, const float* __restrict__ cosT,
    const float* __restrict__ sinT, float* __restrict__ qr,
    float* __restrict__ kr, float* __restrict__ vr)
{
    __shared__ unsigned short Ahi[BMq * BKq];
    __shared__ unsigned short Alo[BMq * BKq];
    __shared__ unsigned short Bhi[BNq * BKq];
    __shared__ unsigned short Blo[BNq * BKq];

    const int tid  = threadIdx.x;
    const int lane = tid & 63;
    const int w    = tid >> 6;
    const int wr   = w >> 1;
    const int wc   = w & 1;
    const int lr   = lane & 15;
    const int kc   = lane >> 4;

    const int m0 = blockIdx.x * BMq;
    const int n0 = blockIdx.y * BNq;

    const int srow = tid >> 1;
    const int kh   = tid & 1;

    f32x4 acc[4][4];
#pragma unroll
    for (int m = 0; m < 4; ++m)
#pragma unroll
        for (int n = 0; n < 4; ++n) acc[m][n] = (f32x4){0.f, 0.f, 0.f, 0.f};

    for (int k0 = 0; k0 < KDIM; k0 += BKq) {
        __syncthreads();
        {
            const float* src = X + (size_t)(m0 + srow) * KDIM + k0 + kh * 16;
            float v[16];
#pragma unroll
            for (int i = 0; i < 4; ++i) ((float4*)v)[i] = ((const float4*)src)[i];
#pragma unroll
            for (int c = 0; c < 2; ++c) {
                int chunk = kh * 2 + c;
                int sidx = srow * 32 + ((chunk ^ ((srow >> 1) & 3)) * 8);
                union { unsigned short u[8]; bf16x8 v8; } hiu, lou;
#pragma unroll
                for (int e = 0; e < 8; ++e) {
                    float x = v[c * 8 + e];
                    unsigned short h = f2bf(x);
                    hiu.u[e] = h;
                    lou.u[e] = f2bf(x - bf2f(h));
                }
                *(bf16x8*)&Ahi[sidx] = hiu.v8;
                *(bf16x8*)&Alo[sidx] = lou.v8;
            }
        }
        {
            const float* src = W + (size_t)(n0 + srow) * KDIM + k0 + kh * 16;
            float v[16];
#pragma unroll
            for (int i = 0; i < 4; ++i) ((float4*)v)[i] = ((const float4*)src)[i];
#pragma unroll
            for (int c = 0; c < 2; ++c) {
                int chunk = kh * 2 + c;
                int sidx = srow * 32 + ((chunk ^ ((srow >> 1) & 3)) * 8);
                union { unsigned short u[8]; bf16x8 v8; } hiu, lou;
#pragma unroll
                for (int e = 0; e < 8; ++e) {
                    float x = v[c * 8 + e];
                    unsigned short h = f2bf(x);
                    hiu.u[e] = h;
                    lou.u[e] = f2bf(x - bf2f(h));
                }
                *(bf16x8*)&Bhi[sidx] = hiu.v8;
                *(bf16x8*)&Blo[sidx] = lou.v8;
            }
        }
        __syncthreads();

        bf16x8 ah[4], al[4], bh[4], bl[4];
#pragma unroll
        for (int m = 0; m < 4; ++m) {
            int row = wr * 64 + m * 16 + lr;
            int idx = row * 32 + ((kc ^ ((row >> 1) & 3)) * 8);
            ah[m] = *(const bf16x8*)&Ahi[idx];
            al[m] = *(const bf16x8*)&Alo[idx];
        }
#pragma unroll
        for (int n = 0; n < 4; ++n) {
            int col = wc * 64 + n * 16 + lr;
            int idx = col * 32 + ((kc ^ ((col >> 1) & 3)) * 8);
            bh[n] = *(const bf16x8*)&Bhi[idx];
            bl[n] = *(const bf16x8*)&Blo[idx];
        }

#pragma unroll
        for (int m = 0; m < 4; ++m)
#pragma unroll
            for (int n = 0; n < 4; ++n) {
                acc[m][n] = __builtin_amdgcn_mfma_f32_16x16x32_bf16(ah[m], bh[n], acc[m][n], 0, 0, 0);
                acc[m][n] = __builtin_amdgcn_mfma_f32_16x16x32_bf16(ah[m], bl[n], acc[m][n], 0, 0, 0);
                acc[m][n] = __builtin_amdgcn_mfma_f32_16x16x32_bf16(al[m], bh[n], acc[m][n], 0, 0, 0);
            }
    }

    const int section = n0 >> 10;
    float* dst = (section == 0) ? qr : (section == 1) ? kr : vr;
    const int hcol = ((n0 & 1023) >> 6) + wc;

    float biasv[2][2];
#pragma unroll
    for (int np = 0; np < 2; ++np) {
        biasv[np][0] = bias[n0 + wc * 64 + np * 16 + lr];
        biasv[np][1] = bias[n0 + wc * 64 + np * 16 + lr + 32];
    }

#pragma unroll
    for (int m = 0; m < 4; ++m) {
#pragma unroll
        for (int j = 0; j < 4; ++j) {
            int grow = m0 + wr * 64 + m * 16 + (lane >> 4) * 4 + j;
            int bidx = grow / T;
            int t = grow - bidx * T;
            float* rowp = dst + (((size_t)bidx * H + hcol) * T + t) * DH;
#pragma unroll
            for (int np = 0; np < 2; ++np) {
                int d = np * 16 + lr;
                float vlo = acc[m][np][j]     + biasv[np][0];
                float vhi = acc[m][np + 2][j] + biasv[np][1];
                if (section < 2) {
                    float c = cosT[t * 32 + d];
                    float s = sinT[t * 32 + d];
                    float nl = vlo * c - vhi * s;
                    float nh = vhi * c + vlo * s;
                    vlo = nl; vhi = nh;
                }
                rowp[d]      = vlo;
                rowp[d + 32] = vhi;
            }
        }
    }
}

// ---------------- Kernel 3: retention via bf16 split-3 MFMA (verified r5) ----------------
#define SBLK 64
#define QBLK 128
#define LDK 72

__global__ __launch_bounds__(256) void retention_mfma_kernel(
    const float* __restrict__ qr, const float* __restrict__ kr,
    const float* __restrict__ vr, float* __restrict__ out)
{
    __shared__ unsigned short Khi[SBLK * LDK], Klo[SBLK * LDK];   // [s][d]
    __shared__ unsigned short Vthi[DH * LDK], Vtlo[DH * LDK];     // [d][s] (transposed)
    __shared__ unsigned short Shi[QBLK * LDK], Slo[QBLK * LDK];   // [r][s]

    const int qb = blockIdx.x;       // 0..5
    const int bh = blockIdx.y;       // 0..127
    const int b = bh >> 4, h = bh & 15;
    const int tid = threadIdx.x;
    const int lane = tid & 63;
    const int w = tid >> 6;
    const int wm = w >> 1;           // q-half 0..1
    const int wc = w & 1;            // col-half 0..1
    const int lr = lane & 15;
    const int lg = lane >> 4;        // 0..3

    bf16x8 qh[4][2], ql[4][2];
    {
        const float* qp = qr + ((size_t)bh * T + (size_t)qb * QBLK + wm * 64) * DH;
#pragma unroll
        for (int m = 0; m < 4; ++m)
#pragma unroll
            for (int kk = 0; kk < 2; ++kk) {
                const float* p = qp + (m * 16 + lr) * DH + kk * 32 + lg * 8;
                float v[8];
                *(float4*)&v[0] = *(const float4*)p;
                *(float4*)&v[4] = *(const float4*)(p + 4);
                union { unsigned short u[8]; bf16x8 v8; } hu, lu;
#pragma unroll
                for (int e = 0; e < 8; ++e) {
                    unsigned short hv = f2bf(v[e]);
                    hu.u[e] = hv;
                    lu.u[e] = f2bf(v[e] - bf2f(hv));
                }
                qh[m][kk] = hu.v8;
                ql[m][kk] = lu.v8;
            }
    }

    f32x4 oacc[4][2];
#pragma unroll
    for (int m = 0; m < 4; ++m)
#pragma unroll
        for (int n = 0; n < 2; ++n) oacc[m][n] = (f32x4){0.f, 0.f, 0.f, 0.f};

    const int qmin = qb * QBLK + wm * 64;
    const int niter = 2 * qb + 2;

    for (int sb = 0; sb < niter; ++sb) {
        __syncthreads();
        {
            int row = tid >> 2, d0 = (tid & 3) * 16;
            const float* src = kr + ((size_t)bh * T + (size_t)sb * SBLK + row) * DH + d0;
            float v[16];
#pragma unroll
            for (int i = 0; i < 4; ++i) *(float4*)&v[i * 4] = *(const float4*)(src + i * 4);
#pragma unroll
            for (int c = 0; c < 2; ++c) {
                union { unsigned short u[8]; bf16x8 v8; } hu, lu;
#pragma unroll
                for (int e = 0; e < 8; ++e) {
                    float x = v[c * 8 + e];
                    unsigned short hv = f2bf(x);
                    hu.u[e] = hv;
                    lu.u[e] = f2bf(x - bf2f(hv));
                }
                int idx = row * LDK + d0 + c * 8;
                *(bf16x8*)&Khi[idx] = hu.v8;
                *(bf16x8*)&Klo[idx] = lu.v8;
            }
        }
        {
            int s0 = (tid >> 4) * 4, d0 = (tid & 15) * 4;
            const float* src = vr + ((size_t)bh * T + (size_t)sb * SBLK + s0) * DH + d0;
            float rv[4][4];
#pragma unroll
            for (int i = 0; i < 4; ++i) *(float4*)&rv[i][0] = *(const float4*)(src + (size_t)i * DH);
#pragma unroll
            for (int j = 0; j < 4; ++j) {
                union { unsigned short u[4]; bf16x4 v4; } hu, lu;
#pragma unroll
                for (int i = 0; i < 4; ++i) {
                    float x = rv[i][j];
                    unsigned short hv = f2bf(x);
                    hu.u[i] = hv;
                    lu.u[i] = f2bf(x - bf2f(hv));
                }
                int idx = (d0 + j) * LDK + s0;
                *(bf16x4*)&Vthi[idx] = hu.v4;
                *(bf16x4*)&Vtlo[idx] = lu.v4;
            }
        }
        __syncthreads();

        const bool active = (sb * SBLK <= qmin + 63);
        if (active) {
            f32x4 sacc[4][2];
#pragma unroll
            for (int m = 0; m < 4; ++m)
#pragma unroll
                for (int n = 0; n < 2; ++n) sacc[m][n] = (f32x4){0.f, 0.f, 0.f, 0.f};

#pragma unroll
            for (int kk = 0; kk < 2; ++kk) {
                bf16x8 kbh[2], kbl[2];
#pragma unroll
                for (int n = 0; n < 2; ++n) {
                    int s = wc * 32 + n * 16 + lr;
                    int idx = s * LDK + kk * 32 + lg * 8;
                    kbh[n] = *(const bf16x8*)&Khi[idx];
                    kbl[n] = *(const bf16x8*)&Klo[idx];
                }
#pragma unroll
                for (int m = 0; m < 4; ++m)
#pragma unroll
                    for (int n = 0; n < 2; ++n) {
                        sacc[m][n] = __builtin_amdgcn_mfma_f32_16x16x32_bf16(qh[m][kk], kbh[n], sacc[m][n], 0, 0, 0);
                        sacc[m][n] = __builtin_amdgcn_mfma_f32_16x16x32_bf16(qh[m][kk], kbl[n], sacc[m][n], 0, 0, 0);
                        sacc[m][n] = __builtin_amdgcn_mfma_f32_16x16x32_bf16(ql[m][kk], kbh[n], sacc[m][n], 0, 0, 0);
                    }
            }

            const bool needmask = (sb * SBLK + 63 > qmin);
#pragma unroll
            for (int m = 0; m < 4; ++m)
#pragma unroll
                for (int n = 0; n < 2; ++n) {
                    int sl = wc * 32 + n * 16 + lr;
                    int sg = sb * SBLK + sl;
#pragma unroll
                    for (int j = 0; j < 4; ++j) {
                        int rl = wm * 64 + m * 16 + lg * 4 + j;
                        int rg = qb * QBLK + rl;
                        float val = sacc[m][n][j];
                        if (needmask && sg > rg) val = 0.f;
                        unsigned short hv = f2bf(val);
                        int idx = rl * LDK + sl;
                        Shi[idx] = hv;
                        Slo[idx] = f2bf(val - bf2f(hv));
                    }
                }
        }
        __syncthreads();
        if (active) {
#pragma unroll
            for (int kk = 0; kk < 2; ++kk) {
                bf16x8 vbh[2], vbl[2], sah[4], sal[4];
#pragma unroll
                for (int n = 0; n < 2; ++n) {
                    int d = wc * 32 + n * 16 + lr;
                    int idx = d * LDK + kk * 32 + lg * 8;
                    vbh[n] = *(const bf16x8*)&Vthi[idx];
                    vbl[n] = *(const bf16x8*)&Vtlo[idx];
                }
#pragma unroll
                for (int m = 0; m < 4; ++m) {
                    int r = wm * 64 + m * 16 + lr;
                    int idx = r * LDK + kk * 32 + lg * 8;
                    sah[m] = *(const bf16x8*)&Shi[idx];
                    sal[m] = *(const bf16x8*)&Slo[idx];
                }
#pragma unroll
                for (int m = 0; m < 4; ++m)
#pragma unroll
                    for (int n = 0; n < 2; ++n) {
                        oacc[m][n] = __builtin_amdgcn_mfma_f32_16x16x32_bf16(sah[m], vbh[n], oacc[m][n], 0, 0, 0);
                        oacc[m][n] = __builtin_amdgcn_mfma_f32_16x16x32_bf16(sah[m], vbl[n], oacc[m][n], 0, 0, 0);
                        oacc[m][n] = __builtin_amdgcn_mfma_f32_16x16x32_bf16(sal[m], vbh[n], oacc[m][n], 0, 0, 0);
                    }
            }
        }
    }

#pragma unroll
    for (int m = 0; m < 4; ++m)
#pragma unroll
        for (int n = 0; n < 2; ++n) {
            int dcol = wc * 32 + n * 16 + lr;
#pragma unroll
            for (int j = 0; j < 4; ++j) {
                int t = qb * QBLK + wm * 64 + m * 16 + lg * 4 + j;
                out[((size_t)b * T + t) * D + h * DH + dcol] = oacc[m][n][j];
            }
        }
}

// ---------------- launch ----------------
extern "C" void kernel_launch(void* const* d_in, const int* in_sizes, int n_in,
                              void* d_out, int out_size, void* d_ws, size_t ws_size,
                              hipStream_t stream) {
    const float* x    = (const float*)d_in[0];
    const float* Wq   = (const float*)d_in[1];
    const float* bq   = (const float*)d_in[2];
    float* out = (float*)d_out;
    float* ws  = (float*)d_ws;

    float* qr   = ws;
    float* kr   = ws + (size_t)QKV_ELEMS;
    float* vr   = ws + (size_t)2 * QKV_ELEMS;
    float* cosT = ws + (size_t)3 * QKV_ELEMS;
    float* sinT = cosT + T * 32;

    const size_t float_bytes = ((size_t)3 * QKV_ELEMS + 2 * T * 32) * sizeof(float);
    unsigned short* Xhi = (unsigned short*)((char*)d_ws + float_bytes);
    unsigned short* Xlo = Xhi + XE;
    unsigned short* Whi = Xlo + XE;
    unsigned short* Wlo = Whi + WE;
    const size_t need = float_bytes + (2 * XE + 2 * WE) * sizeof(unsigned short);

    rope_tables_kernel<<<dim3((T * 32 + 255) / 256), dim3(256), 0, stream>>>(cosT, sinT);

    if (ws_size >= need) {
        split_convert_kernel<<<dim3((int)(XE / 8 / 256)), dim3(256), 0, stream>>>(x,  Xhi, Xlo, (int)(XE / 8));
        split_convert_kernel<<<dim3((int)(WE / 8 / 256)), dim3(256), 0, stream>>>(Wq, Whi, Wlo, (int)(WE / 8));
        qkv_mfma2_kernel<<<dim3(M / BMq, N3 / BNq), dim3(256), 0, stream>>>(
            Xhi, Xlo, Whi, Wlo, bq, cosT, sinT, qr, kr, vr);
    } else {
        qkv_mfma_kernel<<<dim3(M / BMq, N3 / BNq), dim3(256), 0, stream>>>(
            x, Wq, bq, cosT, sinT, qr, kr, vr);
    }

    retention_mfma_kernel<<<dim3(T / QBLK, B * H), dim3(256), 0, stream>>>(qr, kr, vr, out);
}

// Round 8
// 337.852 us; speedup vs baseline: 1.0612x; 1.0612x over previous
//
#include <hip/hip_runtime.h>

// Problem constants
#define B 8
#define T 768
#define D 1024
#define H 16
#define DH 64
#define M (B*T)      // 6144
#define N3 (3*D)     // 3072
#define KDIM D       // 1024
#define QKV_ELEMS (B*H*T*DH)  // 6291456 floats per tensor
#define XE ((size_t)M * KDIM)    // 6291456
#define WE ((size_t)N3 * KDIM)   // 3145728

typedef __attribute__((ext_vector_type(8))) short bf16x8;
typedef __attribute__((ext_vector_type(4))) short bf16x4;
typedef __attribute__((ext_vector_type(4))) float f32x4;

__device__ __forceinline__ unsigned short f2bf(float x) {
    union { float f; unsigned u; } a; a.f = x;
    unsigned r = a.u + 0x7FFFu + ((a.u >> 16) & 1u);
    return (unsigned short)(r >> 16);
}
__device__ __forceinline__ float bf2f(unsigned short h) {
    union { unsigned u; float f; } a; a.u = ((unsigned)h) << 16;
    return a.f;
}

// async global->LDS, 16B per lane; LDS dest is wave-uniform base (HW adds lane*16)
__device__ __forceinline__ void gload_lds16(const void* g, void* l) {
    __builtin_amdgcn_global_load_lds(
        (const __attribute__((address_space(1))) void*)g,
        (__attribute__((address_space(3))) void*)l, 16, 0, 0);
}

// ---------------- Kernel 1: RoPE tables ----------------
__global__ void rope_tables_kernel(float* __restrict__ cosT, float* __restrict__ sinT) {
    int idx = blockIdx.x * blockDim.x + threadIdx.x;  // t*32 + i
    if (idx >= T * 32) return;
    int t = idx >> 5;
    int i = idx & 31;
    float inv_freq = powf(10000.0f, -(float)(2 * i) / 64.0f);
    float ang = (float)t * inv_freq;
    cosT[idx] = cosf(ang);
    sinT[idx] = sinf(ang);
}

// ---------------- Kernel 1b: fp32 -> bf16 hi/lo split (offline, once) ----------------
__global__ __launch_bounds__(256) void split_convert_kernel(
    const float* __restrict__ src, unsigned short* __restrict__ hi,
    unsigned short* __restrict__ lo, int n8)
{
    int i = blockIdx.x * blockDim.x + threadIdx.x;
    if (i >= n8) return;
    const float* p = src + (size_t)i * 8;
    float v[8];
    *(float4*)&v[0] = ((const float4*)p)[0];
    *(float4*)&v[4] = ((const float4*)p)[1];
    union { unsigned short u[8]; uint4 q; } hu, lu;
#pragma unroll
    for (int e = 0; e < 8; ++e) {
        unsigned short h = f2bf(v[e]);
        hu.u[e] = h;
        lu.u[e] = f2bf(v[e] - bf2f(h));
    }
    ((uint4*)hi)[i] = hu.q;
    ((uint4*)lo)[i] = lu.q;
}

#define BMq 128
#define BNq 128
#define BKq 32

// ---------------- Kernel 2 (fast): QKV GEMM, pre-split + gload_lds, single-buffer ----------------
// r6 staging structure (implicit wave-level overlap, 32KB LDS) + r7's HW-verified
// conflict-free involution q ^= (row>>1)&3 on both the pre-swizzled global source
// and the ds_read_b128 fragment reads.
__global__ __launch_bounds__(256) void qkv_mfma2_kernel(
    const unsigned short* __restrict__ Xhi, const unsigned short* __restrict__ Xlo,
    const unsigned short* __restrict__ Whi, const unsigned short* __restrict__ Wlo,
    const float* __restrict__ bias, const float* __restrict__ cosT,
    const float* __restrict__ sinT, float* __restrict__ qr,
    float* __restrict__ kr, float* __restrict__ vr)
{
    __shared__ unsigned short Ah[BMq * BKq], Al[BMq * BKq];
    __shared__ unsigned short Bh[BNq * BKq], Bl[BNq * BKq];   // 32 KB total

    const int tid  = threadIdx.x;
    const int lane = tid & 63;
    const int w    = tid >> 6;      // wave 0..3
    const int wr   = w >> 1;        // wave row 0..1
    const int wc   = w & 1;         // wave col 0..1
    const int lr   = lane & 15;
    const int kc   = lane >> 4;     // k-quarter 0..3

    const int m0 = blockIdx.x * BMq;
    const int n0 = blockIdx.y * BNq;

    f32x4 acc[4][4];
#pragma unroll
    for (int m = 0; m < 4; ++m)
#pragma unroll
        for (int n = 0; n < 4; ++n) acc[m][n] = (f32x4){0.f, 0.f, 0.f, 0.f};

    for (int k0 = 0; k0 < KDIM; k0 += BKq) {
        __syncthreads();
        // ---- stage 4 tiles of 8KB via global_load_lds (2 chunks/wave/array) ----
#pragma unroll
        for (int i = 0; i < 2; ++i) {
            int c   = w * 128 + i * 64 + lane;              // 16B-chunk index 0..511
            int row = c >> 2;
            int qq  = (c & 3) ^ ((row >> 1) & 3);           // pre-swizzled source quarter
            size_t goffA = (size_t)(m0 + row) * KDIM + k0 + qq * 8;
            size_t goffB = (size_t)(n0 + row) * KDIM + k0 + qq * 8;
            int lbase = (w * 128 + i * 64) * 8;             // wave-uniform LDS base (ushort idx)
            gload_lds16(Xhi + goffA, &Ah[lbase]);
            gload_lds16(Xlo + goffA, &Al[lbase]);
            gload_lds16(Whi + goffB, &Bh[lbase]);
            gload_lds16(Wlo + goffB, &Bl[lbase]);
        }
        __syncthreads();   // compiler drains vmcnt before barrier

        // ---- fragment loads (swizzled) ----
        bf16x8 ah[4], al[4], bh[4], bl[4];
#pragma unroll
        for (int m = 0; m < 4; ++m) {
            int r = wr * 64 + m * 16 + lr;
            int idx = r * 32 + (kc ^ ((r >> 1) & 3)) * 8;
            ah[m] = *(const bf16x8*)&Ah[idx];
            al[m] = *(const bf16x8*)&Al[idx];
        }
#pragma unroll
        for (int n = 0; n < 4; ++n) {
            int ccol = wc * 64 + n * 16 + lr;
            int idx = ccol * 32 + (kc ^ ((ccol >> 1) & 3)) * 8;
            bh[n] = *(const bf16x8*)&Bh[idx];
            bl[n] = *(const bf16x8*)&Bl[idx];
        }

        // ---- MFMA: hi*hi + hi*lo + lo*hi ----
#pragma unroll
        for (int m = 0; m < 4; ++m)
#pragma unroll
            for (int n = 0; n < 4; ++n) {
                acc[m][n] = __builtin_amdgcn_mfma_f32_16x16x32_bf16(ah[m], bh[n], acc[m][n], 0, 0, 0);
                acc[m][n] = __builtin_amdgcn_mfma_f32_16x16x32_bf16(ah[m], bl[n], acc[m][n], 0, 0, 0);
                acc[m][n] = __builtin_amdgcn_mfma_f32_16x16x32_bf16(al[m], bh[n], acc[m][n], 0, 0, 0);
            }
    }

    // ---- epilogue: bias + RoPE + scatter to (B,H,T,DH) [verified r3] ----
    const int section = n0 >> 10;                       // 0=q,1=k,2=v
    float* dst = (section == 0) ? qr : (section == 1) ? kr : vr;
    const int hcol = ((n0 & 1023) >> 6) + wc;           // head index

    float biasv[2][2];
#pragma unroll
    for (int np = 0; np < 2; ++np) {
        biasv[np][0] = bias[n0 + wc * 64 + np * 16 + lr];
        biasv[np][1] = bias[n0 + wc * 64 + np * 16 + lr + 32];
    }

#pragma unroll
    for (int m = 0; m < 4; ++m) {
#pragma unroll
        for (int j = 0; j < 4; ++j) {
            int grow = m0 + wr * 64 + m * 16 + (lane >> 4) * 4 + j;
            int bidx = grow / T;
            int t = grow - bidx * T;
            float* rowp = dst + (((size_t)bidx * H + hcol) * T + t) * DH;
#pragma unroll
            for (int np = 0; np < 2; ++np) {
                int d = np * 16 + lr;                   // 0..31
                float vlo = acc[m][np][j]     + biasv[np][0];
                float vhi = acc[m][np + 2][j] + biasv[np][1];
                if (section < 2) {
                    float c = cosT[t * 32 + d];
                    float s = sinT[t * 32 + d];
                    float nl = vlo * c - vhi * s;
                    float nh = vhi * c + vlo * s;
                    vlo = nl; vhi = nh;
                }
                rowp[d]      = vlo;
                rowp[d + 32] = vhi;
            }
        }
    }
}

// ---------------- Kernel 2 (fallback, r5-verified): in-loop split ----------------
__global__ __launch_bounds__(256) void qkv_mfma_kernel(
    const float* __restrict__ X, const float* __restrict__ W,
    const float* __restrict__ bias, const float* __restrict__ cosT,
    const float* __restrict__ sinT, float* __restrict__ qr,
    float* __restrict__ kr, float* __restrict__ vr)
{
    __shared__ unsigned short Ahi[BMq * BKq];
    __shared__ unsigned short Alo[BMq * BKq];
    __shared__ unsigned short Bhi[BNq * BKq];
    __shared__ unsigned short Blo[BNq * BKq];

    const int tid  = threadIdx.x;
    const int lane = tid & 63;
    const int w    = tid >> 6;
    const int wr   = w >> 1;
    const int wc   = w & 1;
    const int lr   = lane & 15;
    const int kc   = lane >> 4;

    const int m0 = blockIdx.x * BMq;
    const int n0 = blockIdx.y * BNq;

    const int srow = tid >> 1;
    const int kh   = tid & 1;

    f32x4 acc[4][4];
#pragma unroll
    for (int m = 0; m < 4; ++m)
#pragma unroll
        for (int n = 0; n < 4; ++n) acc[m][n] = (f32x4){0.f, 0.f, 0.f, 0.f};

    for (int k0 = 0; k0 < KDIM; k0 += BKq) {
        __syncthreads();
        {
            const float* src = X + (size_t)(m0 + srow) * KDIM + k0 + kh * 16;
            float v[16];
#pragma unroll
            for (int i = 0; i < 4; ++i) ((float4*)v)[i] = ((const float4*)src)[i];
#pragma unroll
            for (int c = 0; c < 2; ++c) {
                int chunk = kh * 2 + c;
                int sidx = srow * 32 + ((chunk ^ ((srow >> 1) & 3)) * 8);
                union { unsigned short u[8]; bf16x8 v8; } hiu, lou;
#pragma unroll
                for (int e = 0; e < 8; ++e) {
                    float x = v[c * 8 + e];
                    unsigned short h = f2bf(x);
                    hiu.u[e] = h;
                    lou.u[e] = f2bf(x - bf2f(h));
                }
                *(bf16x8*)&Ahi[sidx] = hiu.v8;
                *(bf16x8*)&Alo[sidx] = lou.v8;
            }
        }
        {
            const float* src = W + (size_t)(n0 + srow) * KDIM + k0 + kh * 16;
            float v[16];
#pragma unroll
            for (int i = 0; i < 4; ++i) ((float4*)v)[i] = ((const float4*)src)[i];
#pragma unroll
            for (int c = 0; c < 2; ++c) {
                int chunk = kh * 2 + c;
                int sidx = srow * 32 + ((chunk ^ ((srow >> 1) & 3)) * 8);
                union { unsigned short u[8]; bf16x8 v8; } hiu, lou;
#pragma unroll
                for (int e = 0; e < 8; ++e) {
                    float x = v[c * 8 + e];
                    unsigned short h = f2bf(x);
                    hiu.u[e] = h;
                    lou.u[e] = f2bf(x - bf2f(h));
                }
                *(bf16x8*)&Bhi[sidx] = hiu.v8;
                *(bf16x8*)&Blo[sidx] = lou.v8;
            }
        }
        __syncthreads();

        bf16x8 ah[4], al[4], bh[4], bl[4];
#pragma unroll
        for (int m = 0; m < 4; ++m) {
            int row = wr * 64 + m * 16 + lr;
            int idx = row * 32 + ((kc ^ ((row >> 1) & 3)) * 8);
            ah[m] = *(const bf16x8*)&Ahi[idx];
            al[m] = *(const bf16x8*)&Alo[idx];
        }
#pragma unroll
        for (int n = 0; n < 4; ++n) {
            int col = wc * 64 + n * 16 + lr;
            int idx = col * 32 + ((kc ^ ((col >> 1) & 3)) * 8);
            bh[n] = *(const bf16x8*)&Bhi[idx];
            bl[n] = *(const bf16x8*)&Blo[idx];
        }

#pragma unroll
        for (int m = 0; m < 4; ++m)
#pragma unroll
            for (int n = 0; n < 4; ++n) {
                acc[m][n] = __builtin_amdgcn_mfma_f32_16x16x32_bf16(ah[m], bh[n], acc[m][n], 0, 0, 0);
                acc[m][n] = __builtin_amdgcn_mfma_f32_16x16x32_bf16(ah[m], bl[n], acc[m][n], 0, 0, 0);
                acc[m][n] = __builtin_amdgcn_mfma_f32_16x16x32_bf16(al[m], bh[n], acc[m][n], 0, 0, 0);
            }
    }

    const int section = n0 >> 10;
    float* dst = (section == 0) ? qr : (section == 1) ? kr : vr;
    const int hcol = ((n0 & 1023) >> 6) + wc;

    float biasv[2][2];
#pragma unroll
    for (int np = 0; np < 2; ++np) {
        biasv[np][0] = bias[n0 + wc * 64 + np * 16 + lr];
        biasv[np][1] = bias[n0 + wc * 64 + np * 16 + lr + 32];
    }

#pragma unroll
    for (int m = 0; m < 4; ++m) {
#pragma unroll
        for (int j = 0; j < 4; ++j) {
            int grow = m0 + wr * 64 + m * 16 + (lane >> 4) * 4 + j;
            int bidx = grow / T;
            int t = grow - bidx * T;
            float* rowp = dst + (((size_t)bidx * H + hcol) * T + t) * DH;
#pragma unroll
            for (int np = 0; np < 2; ++np) {
                int d = np * 16 + lr;
                float vlo = acc[m][np][j]     + biasv[np][0];
                float vhi = acc[m][np + 2][j] + biasv[np][1];
                if (section < 2) {
                    float c = cosT[t * 32 + d];
                    float s = sinT[t * 32 + d];
                    float nl = vlo * c - vhi * s;
                    float nh = vhi * c + vlo * s;
                    vlo = nl; vhi = nh;
                }
                rowp[d]      = vlo;
                rowp[d + 32] = vhi;
            }
        }
    }
}

// ---------------- Kernel 3: retention via bf16 split-3 MFMA (verified r5) ----------------
#define SBLK 64
#define QBLK 128
#define LDK 72

__global__ __launch_bounds__(256) void retention_mfma_kernel(
    const float* __restrict__ qr, const float* __restrict__ kr,
    const float* __restrict__ vr, float* __restrict__ out)
{
    __shared__ unsigned short Khi[SBLK * LDK], Klo[SBLK * LDK];   // [s][d]
    __shared__ unsigned short Vthi[DH * LDK], Vtlo[DH * LDK];     // [d][s] (transposed)
    __shared__ unsigned short Shi[QBLK * LDK], Slo[QBLK * LDK];   // [r][s]

    const int qb = blockIdx.x;       // 0..5
    const int bh = blockIdx.y;       // 0..127
    const int b = bh >> 4, h = bh & 15;
    const int tid = threadIdx.x;
    const int lane = tid & 63;
    const int w = tid >> 6;
    const int wm = w >> 1;           // q-half 0..1
    const int wc = w & 1;            // col-half 0..1
    const int lr = lane & 15;
    const int lg = lane >> 4;        // 0..3

    bf16x8 qh[4][2], ql[4][2];
    {
        const float* qp = qr + ((size_t)bh * T + (size_t)qb * QBLK + wm * 64) * DH;
#pragma unroll
        for (int m = 0; m < 4; ++m)
#pragma unroll
            for (int kk = 0; kk < 2; ++kk) {
                const float* p = qp + (m * 16 + lr) * DH + kk * 32 + lg * 8;
                float v[8];
                *(float4*)&v[0] = *(const float4*)p;
                *(float4*)&v[4] = *(const float4*)(p + 4);
                union { unsigned short u[8]; bf16x8 v8; } hu, lu;
#pragma unroll
                for (int e = 0; e < 8; ++e) {
                    unsigned short hv = f2bf(v[e]);
                    hu.u[e] = hv;
                    lu.u[e] = f2bf(v[e] - bf2f(hv));
                }
                qh[m][kk] = hu.v8;
                ql[m][kk] = lu.v8;
            }
    }

    f32x4 oacc[4][2];
#pragma unroll
    for (int m = 0; m < 4; ++m)
#pragma unroll
        for (int n = 0; n < 2; ++n) oacc[m][n] = (f32x4){0.f, 0.f, 0.f, 0.f};

    const int qmin = qb * QBLK + wm * 64;
    const int niter = 2 * qb + 2;

    for (int sb = 0; sb < niter; ++sb) {
        __syncthreads();
        {
            int row = tid >> 2, d0 = (tid & 3) * 16;
            const float* src = kr + ((size_t)bh * T + (size_t)sb * SBLK + row) * DH + d0;
            float v[16];
#pragma unroll
            for (int i = 0; i < 4; ++i) *(float4*)&v[i * 4] = *(const float4*)(src + i * 4);
#pragma unroll
            for (int c = 0; c < 2; ++c) {
                union { unsigned short u[8]; bf16x8 v8; } hu, lu;
#pragma unroll
                for (int e = 0; e < 8; ++e) {
                    float x = v[c * 8 + e];
                    unsigned short hv = f2bf(x);
                    hu.u[e] = hv;
                    lu.u[e] = f2bf(x - bf2f(hv));
                }
                int idx = row * LDK + d0 + c * 8;
                *(bf16x8*)&Khi[idx] = hu.v8;
                *(bf16x8*)&Klo[idx] = lu.v8;
            }
        }
        {
            int s0 = (tid >> 4) * 4, d0 = (tid & 15) * 4;
            const float* src = vr + ((size_t)bh * T + (size_t)sb * SBLK + s0) * DH + d0;
            float rv[4][4];
#pragma unroll
            for (int i = 0; i < 4; ++i) *(float4*)&rv[i][0] = *(const float4*)(src + (size_t)i * DH);
#pragma unroll
            for (int j = 0; j < 4; ++j) {
                union { unsigned short u[4]; bf16x4 v4; } hu, lu;
#pragma unroll
                for (int i = 0; i < 4; ++i) {
                    float x = rv[i][j];
                    unsigned short hv = f2bf(x);
                    hu.u[i] = hv;
                    lu.u[i] = f2bf(x - bf2f(hv));
                }
                int idx = (d0 + j) * LDK + s0;
                *(bf16x4*)&Vthi[idx] = hu.v4;
                *(bf16x4*)&Vtlo[idx] = lu.v4;
            }
        }
        __syncthreads();

        const bool active = (sb * SBLK <= qmin + 63);
        if (active) {
            f32x4 sacc[4][2];
#pragma unroll
            for (int m = 0; m < 4; ++m)
#pragma unroll
                for (int n = 0; n < 2; ++n) sacc[m][n] = (f32x4){0.f, 0.f, 0.f, 0.f};

#pragma unroll
            for (int kk = 0; kk < 2; ++kk) {
                bf16x8 kbh[2], kbl[2];
#pragma unroll
                for (int n = 0; n < 2; ++n) {
                    int s = wc * 32 + n * 16 + lr;
                    int idx = s * LDK + kk * 32 + lg * 8;
                    kbh[n] = *(const bf16x8*)&Khi[idx];
                    kbl[n] = *(const bf16x8*)&Klo[idx];
                }
#pragma unroll
                for (int m = 0; m < 4; ++m)
#pragma unroll
                    for (int n = 0; n < 2; ++n) {
                        sacc[m][n] = __builtin_amdgcn_mfma_f32_16x16x32_bf16(qh[m][kk], kbh[n], sacc[m][n], 0, 0, 0);
                        sacc[m][n] = __builtin_amdgcn_mfma_f32_16x16x32_bf16(qh[m][kk], kbl[n], sacc[m][n], 0, 0, 0);
                        sacc[m][n] = __builtin_amdgcn_mfma_f32_16x16x32_bf16(ql[m][kk], kbh[n], sacc[m][n], 0, 0, 0);
                    }
            }

            const bool needmask = (sb * SBLK + 63 > qmin);
#pragma unroll
            for (int m = 0; m < 4; ++m)
#pragma unroll
                for (int n = 0; n < 2; ++n) {
                    int sl = wc * 32 + n * 16 + lr;
                    int sg = sb * SBLK + sl;
#pragma unroll
                    for (int j = 0; j < 4; ++j) {
                        int rl = wm * 64 + m * 16 + lg * 4 + j;
                        int rg = qb * QBLK + rl;
                        float val = sacc[m][n][j];
                        if (needmask && sg > rg) val = 0.f;
                        unsigned short hv = f2bf(val);
                        int idx = rl * LDK + sl;
                        Shi[idx] = hv;
                        Slo[idx] = f2bf(val - bf2f(hv));
                    }
                }
        }
        __syncthreads();
        if (active) {
#pragma unroll
            for (int kk = 0; kk < 2; ++kk) {
                bf16x8 vbh[2], vbl[2], sah[4], sal[4];
#pragma unroll
                for (int n = 0; n < 2; ++n) {
                    int d = wc * 32 + n * 16 + lr;
                    int idx = d * LDK + kk * 32 + lg * 8;
                    vbh[n] = *(const bf16x8*)&Vthi[idx];
                    vbl[n] = *(const bf16x8*)&Vtlo[idx];
                }
#pragma unroll
                for (int m = 0; m < 4; ++m) {
                    int r = wm * 64 + m * 16 + lr;
                    int idx = r * LDK + kk * 32 + lg * 8;
                    sah[m] = *(const bf16x8*)&Shi[idx];
                    sal[m] = *(const bf16x8*)&Slo[idx];
                }
#pragma unroll
                for (int m = 0; m < 4; ++m)
#pragma unroll
                    for (int n = 0; n < 2; ++n) {
                        oacc[m][n] = __builtin_amdgcn_mfma_f32_16x16x32_bf16(sah[m], vbh[n], oacc[m][n], 0, 0, 0);
                        oacc[m][n] = __builtin_amdgcn_mfma_f32_16x16x32_bf16(sah[m], vbl[n], oacc[m][n], 0, 0, 0);
                        oacc[m][n] = __builtin_amdgcn_mfma_f32_16x16x32_bf16(sal[m], vbh[n], oacc[m][n], 0, 0, 0);
                    }
            }
        }
    }

#pragma unroll
    for (int m = 0; m < 4; ++m)
#pragma unroll
        for (int n = 0; n < 2; ++n) {
            int dcol = wc * 32 + n * 16 + lr;
#pragma unroll
            for (int j = 0; j < 4; ++j) {
                int t = qb * QBLK + wm * 64 + m * 16 + lg * 4 + j;
                out[((size_t)b * T + t) * D + h * DH + dcol] = oacc[m][n][j];
            }
        }
}

// ---------------- launch ----------------
extern "C" void kernel_launch(void* const* d_in, const int* in_sizes, int n_in,
                              void* d_out, int out_size, void* d_ws, size_t ws_size,
                              hipStream_t stream) {
    const float* x    = (const float*)d_in[0];
    const float* Wq   = (const float*)d_in[1];
    const float* bq   = (const float*)d_in[2];
    float* out = (float*)d_out;
    float* ws  = (float*)d_ws;

    float* qr   = ws;
    float* kr   = ws + (size_t)QKV_ELEMS;
    float* vr   = ws + (size_t)2 * QKV_ELEMS;
    float* cosT = ws + (size_t)3 * QKV_ELEMS;
    float* sinT = cosT + T * 32;

    const size_t float_bytes = ((size_t)3 * QKV_ELEMS + 2 * T * 32) * sizeof(float);
    unsigned short* Xhi = (unsigned short*)((char*)d_ws + float_bytes);
    unsigned short* Xlo = Xhi + XE;
    unsigned short* Whi = Xlo + XE;
    unsigned short* Wlo = Whi + WE;
    const size_t need = float_bytes + (2 * XE + 2 * WE) * sizeof(unsigned short);

    rope_tables_kernel<<<dim3((T * 32 + 255) / 256), dim3(256), 0, stream>>>(cosT, sinT);

    if (ws_size >= need) {
        split_convert_kernel<<<dim3((int)(XE / 8 / 256)), dim3(256), 0, stream>>>(x,  Xhi, Xlo, (int)(XE / 8));
        split_convert_kernel<<<dim3((int)(WE / 8 / 256)), dim3(256), 0, stream>>>(Wq, Whi, Wlo, (int)(WE / 8));
        qkv_mfma2_kernel<<<dim3(M / BMq, N3 / BNq), dim3(256), 0, stream>>>(
            Xhi, Xlo, Whi, Wlo, bq, cosT, sinT, qr, kr, vr);
    } else {
        qkv_mfma_kernel<<<dim3(M / BMq, N3 / BNq), dim3(256), 0, stream>>>(
            x, Wq, bq, cosT, sinT, qr, kr, vr);
    }

    retention_mfma_kernel<<<dim3(T / QBLK, B * H), dim3(256), 0, stream>>>(qr, kr, vr, out);
}